// Round 18
// baseline (118.422 us; speedup 1.0000x reference)
//
#include <hip/hip_runtime.h>
#include <hip/hip_bf16.h>

// TripletLoss N=8192, D=128. Round 19: best-of-ledger recombination.
// Round-18 post-mortem: triangular halved compute (MfmaUtil 11.7->5.8,
// conflicts halved) but ~1.5M device-scope atomics to a shared 64KB accg
// cost it all back (WRITE_SIZE 16.8MB of coherence writebacks; 56.9us).
// Structure ledger: r8 2-barrier 49.5 | small-dbuf 55.0 | big-dbuf 58.4 |
// 32x32 61-73 | triangular 56.9 -- r8's loop is the floor. Total ledger:
// dropping the memset+bucket dispatch (r17) saved ~10us. This round runs
// the never-tested combination: r8's proven 49.5us loop + in-block corr
// label-scan (no memset, no gcnt/gslot), 3 dispatches.
// t-units: Fb,x2 pre-scaled by AK1=sqrt2*log2(e); C-init -(x2i+x2j)/2 =>
// acc = -AK1^2*d2/2; t=sqrt(-acc); exp(-dist)=exp2(-t); dist=t*ln2;
// positives exp(dist-30)=exp2(t+C2).

typedef __bf16 bf16x8 __attribute__((ext_vector_type(8)));
typedef float f32x4 __attribute__((ext_vector_type(4)));

#define NROWS 8192
#define DIM 128
#define JTILE 64
#define LDS_STRIDE 136    // 128+8 bf16 pad: 272B rows (17x16B, odd -> b128 spread)
#define NLABELS 512
#define GCAP 64           // max rows/label (E=16; P(>64) ~ 1e-30)
#define JSPLIT 16
#define JSPAN (NROWS / JSPLIT)   // 512
#define JITERS (JSPAN / JTILE)   // 8
#define MARGIN_F 0.3f
#define AK1F 2.04027892f      // sqrt2 * log2(e)
#define AK1SQ 4.16273807f     // AK1^2
#define EPS_T 2.08137e-8f     // AK1^2 * 5e-9 (matches reference clip(d2,1e-8))
#define C2F (-43.2808512f)    // -30*log2(e)
#define LN2F 0.69314718f

// ---------------- kernel 1: scaled bf16 cast + row norms + zero gstat ------
__global__ __launch_bounds__(256) void prep_kernel(const float* __restrict__ F,
                                                   __hip_bfloat16* __restrict__ Fb,
                                                   float* __restrict__ x2,
                                                   float* __restrict__ gstat) {
    const int tid = threadIdx.x;
    const int wave = tid >> 6, lane = tid & 63;
    const int row = blockIdx.x * 4 + wave;
    float2 f = ((const float2*)(F + (size_t)row * DIM))[lane];
    f.x *= AK1F; f.y *= AK1F;
    ((__hip_bfloat162*)(Fb + (size_t)row * DIM))[lane] = __float22bfloat162_rn(f);
    float ss = f.x * f.x + f.y * f.y;
#pragma unroll
    for (int m = 32; m > 0; m >>= 1) ss += __shfl_xor(ss, m, 64);
    if (lane == 0) x2[row] = ss;
    if (blockIdx.x == 0 && tid < 4) gstat[tid] = 0.f;
}

// ---------------- kernel 2: fused GEMM + mining; corr head on by<4 ---------
// 64 i-rows per block, 16 per wave (16x16 MFMA); r8's proven 2-barrier loop.
template<bool DIAG>
__device__ __forceinline__ void tile_body(const __hip_bfloat16* __restrict__ sB,
                                          const float* __restrict__ sX2h,
                                          const bf16x8 (&a)[4],
                                          const float (&x2ih)[4],
                                          float (&nl4)[4], float (&ns4)[4],
                                          int lm, int quad, int ig0, int jbase) {
#pragma unroll
    for (int jt = 0; jt < 4; ++jt) {
        const int jl = jt * 16 + lm;
        const __hip_bfloat16* bp = sB + jl * LDS_STRIDE + quad * 8;
        const float xjh = sX2h[jl];
        f32x4 acc;
#pragma unroll
        for (int r = 0; r < 4; ++r) acc[r] = x2ih[r] + xjh;
#pragma unroll
        for (int kc = 0; kc < 4; ++kc) {
            bf16x8 b = *(const bf16x8*)(bp + kc * 32);
            acc = __builtin_amdgcn_mfma_f32_16x16x32_bf16(a[kc], b, acc, 0, 0, 0);
        }
        const int dj = jbase + jl - ig0;   // self-pair iff dj == r
#pragma unroll
        for (int r = 0; r < 4; ++r) {
            float d2h = fmaxf(-acc[r], EPS_T);          // = AK1^2*d2/2, clipped
            float t = __builtin_amdgcn_sqrtf(d2h);      // dist = t*ln2
            float ne = __builtin_amdgcn_exp2f(-t);      // exp(-dist)
            if (DIAG) ne = (dj == r) ? 0.f : ne;
            nl4[r] += ne;
            ns4[r] = fmaf(ne, t, ns4[r]);
        }
    }
}

__global__ __launch_bounds__(256, 4) void pairs_kernel(
        const __hip_bfloat16* __restrict__ Fb,
        const float* __restrict__ x2,
        const float* __restrict__ F,
        const int* __restrict__ labels,
        float2* __restrict__ partial,
        float4* __restrict__ corr) {
    __shared__ __hip_bfloat16 sB[JTILE * LDS_STRIDE];   // 17.4 KB
    __shared__ float sX2[JTILE];                        // -0.5 * x2j
    __shared__ int sIdx[GCAP];
    __shared__ int sCnt;

    const int tid = threadIdx.x;
    const int bx = blockIdx.x, by = blockIdx.y;

    // ---- corr head: 512 blocks (by<4), one label each, before the j-loop --
    if (by < 4) {
        const int L = by * 128 + bx;
        if (tid == 0) sCnt = 0;
        __syncthreads();
        for (int it = 0; it < NROWS / 1024; ++it) {     // 8 iterations
            const int g = it * 1024 + tid * 4;
            int4 lv = *(const int4*)(labels + g);
#pragma unroll
            for (int k = 0; k < 4; ++k) {
                int lab = (k == 0) ? lv.x : (k == 1) ? lv.y : (k == 2) ? lv.z : lv.w;
                if (lab == L) {
                    int pos = atomicAdd(&sCnt, 1);
                    if (pos < GCAP) sIdx[pos] = g + k;
                }
            }
        }
        __syncthreads();
        const int gsz = sCnt < GCAP ? sCnt : GCAP;
        if (gsz > 0) {
            float* sAcc = (float*)sB;          // overlay, pre-staging
            float* plA = sAcc;
            float* psA = sAcc + GCAP;
            float* nlA = sAcc + 2 * GCAP;
            float* nsA = sAcc + 3 * GCAP;
            if (tid < GCAP) { plA[tid] = 0.f; psA[tid] = 0.f; nlA[tid] = 0.f; nsA[tid] = 0.f; }
            __syncthreads();
            const int npair = gsz * gsz;
            for (int p = tid; p < npair; p += 256) {
                const int aI = p / gsz, bI = p - aI * gsz;
                if (aI == bI) continue;
                const float4* pa = (const float4*)(F + (size_t)sIdx[aI] * DIM);
                const float4* pb = (const float4*)(F + (size_t)sIdx[bI] * DIM);
                float dot = 0.f, ssa = 0.f, ssb = 0.f;
#pragma unroll 8
                for (int u = 0; u < 32; ++u) {
                    float4 va = pa[u], vb = pb[u];
                    dot = fmaf(va.x, vb.x, fmaf(va.y, vb.y, fmaf(va.z, vb.z, fmaf(va.w, vb.w, dot))));
                    ssa = fmaf(va.x, va.x, fmaf(va.y, va.y, fmaf(va.z, va.z, fmaf(va.w, va.w, ssa))));
                    ssb = fmaf(vb.x, vb.x, fmaf(vb.y, vb.y, fmaf(vb.z, vb.z, fmaf(vb.w, vb.w, ssb))));
                }
                float d2h = fmaxf((0.5f * (ssa + ssb) - dot) * AK1SQ, EPS_T);
                float t = __builtin_amdgcn_sqrtf(d2h);
                float ne = __builtin_amdgcn_exp2f(-t);
                float pe = __builtin_amdgcn_exp2f(t + C2F);
                unsafeAtomicAdd(&nlA[aI], ne);
                unsafeAtomicAdd(&nsA[aI], ne * t);
                unsafeAtomicAdd(&plA[aI], pe);
                unsafeAtomicAdd(&psA[aI], pe * t);
            }
            __syncthreads();
            if (tid < gsz)
                corr[sIdx[tid]] = make_float4(plA[tid], psA[tid], -nlA[tid], -nsA[tid]);
        }
        __syncthreads();   // corr LDS use done before staging overwrites
    }

    // ---- A-fragments + x2i (r8 mapping) ----
    const int wave = tid >> 6;
    const int lane = tid & 63;
    const int quad = lane >> 4;
    const int lm = lane & 15;
    const int rbase = bx * 64 + wave * 16;

    bf16x8 a[4];
#pragma unroll
    for (int kc = 0; kc < 4; ++kc)
        a[kc] = *(const bf16x8*)(Fb + (size_t)(rbase + lm) * DIM + kc * 32 + quad * 8);

    const int ig0 = rbase + quad * 4;
    float x2ih[4];
#pragma unroll
    for (int r = 0; r < 4; ++r) x2ih[r] = -0.5f * x2[ig0 + r];

    float nl4[4] = {0,0,0,0}, ns4[4] = {0,0,0,0};

    const int j0 = by * JSPAN;
    const int djb = bx - by * JITERS;   // jb holding the diagonal (if in range)

    for (int jb = 0; jb < JITERS; ++jb) {
        const int jbase = j0 + jb * JTILE;
        __syncthreads();   // previous tile's readers done
#pragma unroll
        for (int s = 0; s < 4; ++s) {
            int c = tid + s * 256;
            int jr = c >> 4, ck = c & 15;
            *(bf16x8*)(sB + jr * LDS_STRIDE + ck * 8) =
                *(const bf16x8*)(Fb + (size_t)(jbase + jr) * DIM + ck * 8);
        }
        if (tid < JTILE) sX2[tid] = -0.5f * x2[jbase + tid];
        __syncthreads();

        if (jb == djb)
            tile_body<true >(sB, sX2, a, x2ih, nl4, ns4, lm, quad, ig0, jbase);
        else
            tile_body<false>(sB, sX2, a, x2ih, nl4, ns4, lm, quad, ig0, jbase);
    }

    // reduce over the 16 lanes (lm) sharing each i-row
#pragma unroll
    for (int m = 1; m < 16; m <<= 1) {
#pragma unroll
        for (int r = 0; r < 4; ++r) {
            nl4[r] += __shfl_xor(nl4[r], m, 64);
            ns4[r] += __shfl_xor(ns4[r], m, 64);
        }
    }
    if (lm == 0) {
#pragma unroll
        for (int r = 0; r < 4; ++r)
            partial[(size_t)by * NROWS + ig0 + r] = make_float2(nl4[r], ns4[r]);
    }
}

// ---------------- kernel 3: per-row loss, reduce, final divide -------------
__global__ __launch_bounds__(256) void finalize_kernel(const float2* __restrict__ partial,
                                                       const float4* __restrict__ corr,
                                                       float* __restrict__ gstat,
                                                       float* __restrict__ out) {
    const int row = blockIdx.x * 256 + threadIdx.x;
    float4 c = corr[row];
    float nl = c.z, ns = c.w;    // negative corrections (subtract same-label mass)
#pragma unroll
    for (int s = 0; s < JSPLIT; ++s) {
        float2 p = partial[(size_t)s * NROWS + row];
        nl += p.x; ns += p.y;
    }
    float sum = 0.f, cnt = 0.f;
    if (c.x > 0.f && nl > 0.f) {
        float x = fmaf(LN2F, c.y / c.x - ns / nl, MARGIN_F);   // wp - wn + margin
        sum = fmaxf(x, 0.f) + log1pf(__expf(-fabsf(x)));       // stable softplus
        cnt = 1.f;
    }
#pragma unroll
    for (int m = 32; m > 0; m >>= 1) {
        sum += __shfl_xor(sum, m, 64);
        cnt += __shfl_xor(cnt, m, 64);
    }
    __shared__ float sS[4], sC[4];
    const int wave = threadIdx.x >> 6, lane = threadIdx.x & 63;
    if (lane == 0) { sS[wave] = sum; sC[wave] = cnt; }
    __syncthreads();
    if (threadIdx.x == 0) {
        unsafeAtomicAdd(&gstat[0], sS[0] + sS[1] + sS[2] + sS[3]);
        unsafeAtomicAdd(&gstat[1], sC[0] + sC[1] + sC[2] + sC[3]);
        __threadfence();
        unsigned t = atomicAdd((unsigned*)(gstat + 2), 1u);
        if (t == (unsigned)(gridDim.x - 1)) {
            float s2 = unsafeAtomicAdd(&gstat[0], 0.f);   // L2 reads
            float c2 = unsafeAtomicAdd(&gstat[1], 0.f);
            out[0] = s2 / fmaxf(c2, 1.f);
        }
    }
}

extern "C" void kernel_launch(void* const* d_in, const int* in_sizes, int n_in,
                              void* d_out, int out_size, void* d_ws, size_t ws_size,
                              hipStream_t stream) {
    const float* F = (const float*)d_in[0];
    const int* labels = (const int*)d_in[1];
    float* out = (float*)d_out;

    char* ws = (char*)d_ws;
    __hip_bfloat16* Fb = (__hip_bfloat16*)ws;                        // 2 MB
    size_t off = (size_t)NROWS * DIM * 2;
    float* x2 = (float*)(ws + off);    off += (size_t)NROWS * 4;     // 32 KB
    float4* corr = (float4*)(ws + off); off += (size_t)NROWS * 16;   // 128 KB
    float2* partial = (float2*)(ws + off);                           // 1 MB
    off += (size_t)JSPLIT * NROWS * 8;
    float* gstat = (float*)(ws + off);                               // 16 B

    prep_kernel<<<NROWS / 4, 256, 0, stream>>>(F, Fb, x2, gstat);
    pairs_kernel<<<dim3(NROWS / 64, JSPLIT), 256, 0, stream>>>(
        Fb, x2, F, labels, partial, corr);
    finalize_kernel<<<NROWS / 256, 256, 0, stream>>>(partial, corr, gstat, out);
}

// Round 19
// 116.438 us; speedup vs baseline: 1.0170x; 1.0170x over previous
//
#include <hip/hip_runtime.h>
#include <hip/hip_bf16.h>

// TripletLoss N=8192, D=128. Round 20: r8 loop + tail-free spread corr head.
// Round-19 post-mortem: same main loop as r8 but pairs 63.1 vs 49.5 -- the
// scan + f32-dots corr head is a MAKESPAN TAIL: one block per label, label
// sizes ~Poisson(16), worst label (~gsz 30+) => gsz^2 pairs x 384 FMA x 1KB
// loads on ONE block extends the whole dispatch >10us. Fix: (a) bf16 dots
// from Fb + x2 (verbatim r5-r8 head, absmax 0.0 proven, 3x cheaper);
// (b) spread each label over 4 blocks (grid 2048 = 512 labels x 4): block
// b -> label L=b>>2, quarter q=b&3, rows aI in {q,q+4,...}. Worst-block
// head ~12x smaller; each corr row written by exactly ONE block (aI mod 4
// -> unique owner), no atomics/zeroing added. All blocks scan (uniform,
// ~2us aggregate L2).
// t-units: Fb,x2 pre-scaled by AK1=sqrt2*log2(e); C-init -(x2i+x2j)/2 =>
// acc = -AK1^2*d2/2; t=sqrt(-acc); exp(-dist)=exp2(-t); dist=t*ln2;
// positives exp(dist-30)=exp2(t+C2).

typedef __bf16 bf16x8 __attribute__((ext_vector_type(8)));
typedef float f32x4 __attribute__((ext_vector_type(4)));

#define NROWS 8192
#define DIM 128
#define JTILE 64
#define LDS_STRIDE 136    // 128+8 bf16 pad: 272B rows (17x16B, odd -> b128 spread)
#define NLABELS 512
#define GCAP 64           // max rows/label (E=16; P(>64) ~ 1e-30)
#define JSPLIT 16
#define JSPAN (NROWS / JSPLIT)   // 512
#define JITERS (JSPAN / JTILE)   // 8
#define MARGIN_F 0.3f
#define AK1F 2.04027892f      // sqrt2 * log2(e)
#define EPS_T 2.08137e-8f     // AK1^2 * 5e-9 (matches reference clip(d2,1e-8))
#define C2F (-43.2808512f)    // -30*log2(e)
#define LN2F 0.69314718f

// ---------------- kernel 1: scaled bf16 cast + row norms + zero gstat ------
__global__ __launch_bounds__(256) void prep_kernel(const float* __restrict__ F,
                                                   __hip_bfloat16* __restrict__ Fb,
                                                   float* __restrict__ x2,
                                                   float* __restrict__ gstat) {
    const int tid = threadIdx.x;
    const int wave = tid >> 6, lane = tid & 63;
    const int row = blockIdx.x * 4 + wave;
    float2 f = ((const float2*)(F + (size_t)row * DIM))[lane];
    f.x *= AK1F; f.y *= AK1F;
    ((__hip_bfloat162*)(Fb + (size_t)row * DIM))[lane] = __float22bfloat162_rn(f);
    float ss = f.x * f.x + f.y * f.y;
#pragma unroll
    for (int m = 32; m > 0; m >>= 1) ss += __shfl_xor(ss, m, 64);
    if (lane == 0) x2[row] = ss;
    if (blockIdx.x == 0 && tid < 4) gstat[tid] = 0.f;
}

// ---------------- kernel 2: fused GEMM + mining; spread corr head ----------
// 64 i-rows per block, 16 per wave (16x16 MFMA); r8's proven 2-barrier loop.
template<bool DIAG>
__device__ __forceinline__ void tile_body(const __hip_bfloat16* __restrict__ sB,
                                          const float* __restrict__ sX2h,
                                          const bf16x8 (&a)[4],
                                          const float (&x2ih)[4],
                                          float (&nl4)[4], float (&ns4)[4],
                                          int lm, int quad, int ig0, int jbase) {
#pragma unroll
    for (int jt = 0; jt < 4; ++jt) {
        const int jl = jt * 16 + lm;
        const __hip_bfloat16* bp = sB + jl * LDS_STRIDE + quad * 8;
        const float xjh = sX2h[jl];
        f32x4 acc;
#pragma unroll
        for (int r = 0; r < 4; ++r) acc[r] = x2ih[r] + xjh;
#pragma unroll
        for (int kc = 0; kc < 4; ++kc) {
            bf16x8 b = *(const bf16x8*)(bp + kc * 32);
            acc = __builtin_amdgcn_mfma_f32_16x16x32_bf16(a[kc], b, acc, 0, 0, 0);
        }
        const int dj = jbase + jl - ig0;   // self-pair iff dj == r
#pragma unroll
        for (int r = 0; r < 4; ++r) {
            float d2h = fmaxf(-acc[r], EPS_T);          // = AK1^2*d2/2, clipped
            float t = __builtin_amdgcn_sqrtf(d2h);      // dist = t*ln2
            float ne = __builtin_amdgcn_exp2f(-t);      // exp(-dist)
            if (DIAG) ne = (dj == r) ? 0.f : ne;
            nl4[r] += ne;
            ns4[r] = fmaf(ne, t, ns4[r]);
        }
    }
}

__global__ __launch_bounds__(256, 4) void pairs_kernel(
        const __hip_bfloat16* __restrict__ Fb,
        const float* __restrict__ x2,
        const int* __restrict__ labels,
        float2* __restrict__ partial,
        float4* __restrict__ corr) {
    __shared__ __hip_bfloat16 sB[JTILE * LDS_STRIDE];   // 17.4 KB
    __shared__ float sX2[JTILE];                        // -0.5 * x2j
    __shared__ int sIdx[GCAP];
    __shared__ int sCnt;

    const int tid = threadIdx.x;
    const int bx = blockIdx.x, by = blockIdx.y;

    // ---- spread corr head: block b -> label b>>2, quarter b&3 -------------
    {
        const int b = by * 128 + bx;          // [0, 2048)
        const int L = b >> 2, q = b & 3;
        if (tid == 0) sCnt = 0;
        __syncthreads();
        for (int it = 0; it < NROWS / 1024; ++it) {     // 8 iterations
            const int g = it * 1024 + tid * 4;
            int4 lv = *(const int4*)(labels + g);
#pragma unroll
            for (int k = 0; k < 4; ++k) {
                int lab = (k == 0) ? lv.x : (k == 1) ? lv.y : (k == 2) ? lv.z : lv.w;
                if (lab == L) {
                    int pos = atomicAdd(&sCnt, 1);
                    if (pos < GCAP) sIdx[pos] = g + k;
                }
            }
        }
        __syncthreads();
        const int gsz = sCnt < GCAP ? sCnt : GCAP;
        if (gsz > q) {                         // block-uniform condition
            float* sAcc = (float*)sB;          // overlay, pre-staging
            float* plA = sAcc;
            float* psA = sAcc + GCAP;
            float* nlA = sAcc + 2 * GCAP;
            float* nsA = sAcc + 3 * GCAP;
            if (tid < GCAP) { plA[tid] = 0.f; psA[tid] = 0.f; nlA[tid] = 0.f; nsA[tid] = 0.f; }
            __syncthreads();
            const int nA = (gsz - q + 3) >> 2;        // handled aI count
            const int npair = nA * gsz;
            for (int p = tid; p < npair; p += 256) {
                const int aI = q + 4 * (p / gsz);
                const int bI = p % gsz;
                if (aI == bI) continue;
                const int ia = sIdx[aI], ib = sIdx[bI];
                const bf16x8* pa = (const bf16x8*)(Fb + (size_t)ia * DIM);
                const bf16x8* pb = (const bf16x8*)(Fb + (size_t)ib * DIM);
                float dot = 0.f;
#pragma unroll 4
                for (int u = 0; u < 16; ++u) {
                    bf16x8 va = pa[u], vb = pb[u];
#pragma unroll
                    for (int e = 0; e < 8; ++e)
                        dot = fmaf((float)va[e], (float)vb[e], dot);
                }
                float d2h = fmaxf(0.5f * (x2[ia] + x2[ib]) - dot, EPS_T);  // t-units
                float t = __builtin_amdgcn_sqrtf(d2h);
                float ne = __builtin_amdgcn_exp2f(-t);
                float pe = __builtin_amdgcn_exp2f(t + C2F);
                unsafeAtomicAdd(&nlA[aI], ne);
                unsafeAtomicAdd(&nsA[aI], ne * t);
                unsafeAtomicAdd(&plA[aI], pe);
                unsafeAtomicAdd(&psA[aI], pe * t);
            }
            __syncthreads();
            if (tid < gsz && (tid & 3) == q)   // unique owner per row
                corr[sIdx[tid]] = make_float4(plA[tid], psA[tid], -nlA[tid], -nsA[tid]);
        }
        __syncthreads();   // head's LDS use done before staging overwrites
    }

    // ---- A-fragments + x2i (r8 mapping) ----
    const int wave = tid >> 6;
    const int lane = tid & 63;
    const int quad = lane >> 4;
    const int lm = lane & 15;
    const int rbase = bx * 64 + wave * 16;

    bf16x8 a[4];
#pragma unroll
    for (int kc = 0; kc < 4; ++kc)
        a[kc] = *(const bf16x8*)(Fb + (size_t)(rbase + lm) * DIM + kc * 32 + quad * 8);

    const int ig0 = rbase + quad * 4;
    float x2ih[4];
#pragma unroll
    for (int r = 0; r < 4; ++r) x2ih[r] = -0.5f * x2[ig0 + r];

    float nl4[4] = {0,0,0,0}, ns4[4] = {0,0,0,0};

    const int j0 = by * JSPAN;
    const int djb = bx - by * JITERS;   // jb holding the diagonal (if in range)

    for (int jb = 0; jb < JITERS; ++jb) {
        const int jbase = j0 + jb * JTILE;
        __syncthreads();   // previous tile's readers done
#pragma unroll
        for (int s = 0; s < 4; ++s) {
            int c = tid + s * 256;
            int jr = c >> 4, ck = c & 15;
            *(bf16x8*)(sB + jr * LDS_STRIDE + ck * 8) =
                *(const bf16x8*)(Fb + (size_t)(jbase + jr) * DIM + ck * 8);
        }
        if (tid < JTILE) sX2[tid] = -0.5f * x2[jbase + tid];
        __syncthreads();

        if (jb == djb)
            tile_body<true >(sB, sX2, a, x2ih, nl4, ns4, lm, quad, ig0, jbase);
        else
            tile_body<false>(sB, sX2, a, x2ih, nl4, ns4, lm, quad, ig0, jbase);
    }

    // reduce over the 16 lanes (lm) sharing each i-row
#pragma unroll
    for (int m = 1; m < 16; m <<= 1) {
#pragma unroll
        for (int r = 0; r < 4; ++r) {
            nl4[r] += __shfl_xor(nl4[r], m, 64);
            ns4[r] += __shfl_xor(ns4[r], m, 64);
        }
    }
    if (lm == 0) {
#pragma unroll
        for (int r = 0; r < 4; ++r)
            partial[(size_t)by * NROWS + ig0 + r] = make_float2(nl4[r], ns4[r]);
    }
}

// ---------------- kernel 3: per-row loss, reduce, final divide -------------
__global__ __launch_bounds__(256) void finalize_kernel(const float2* __restrict__ partial,
                                                       const float4* __restrict__ corr,
                                                       float* __restrict__ gstat,
                                                       float* __restrict__ out) {
    const int row = blockIdx.x * 256 + threadIdx.x;
    float4 c = corr[row];
    float nl = c.z, ns = c.w;    // negative corrections (subtract same-label mass)
#pragma unroll
    for (int s = 0; s < JSPLIT; ++s) {
        float2 p = partial[(size_t)s * NROWS + row];
        nl += p.x; ns += p.y;
    }
    float sum = 0.f, cnt = 0.f;
    if (c.x > 0.f && nl > 0.f) {
        float x = fmaf(LN2F, c.y / c.x - ns / nl, MARGIN_F);   // wp - wn + margin
        sum = fmaxf(x, 0.f) + log1pf(__expf(-fabsf(x)));       // stable softplus
        cnt = 1.f;
    }
#pragma unroll
    for (int m = 32; m > 0; m >>= 1) {
        sum += __shfl_xor(sum, m, 64);
        cnt += __shfl_xor(cnt, m, 64);
    }
    __shared__ float sS[4], sC[4];
    const int wave = threadIdx.x >> 6, lane = threadIdx.x & 63;
    if (lane == 0) { sS[wave] = sum; sC[wave] = cnt; }
    __syncthreads();
    if (threadIdx.x == 0) {
        unsafeAtomicAdd(&gstat[0], sS[0] + sS[1] + sS[2] + sS[3]);
        unsafeAtomicAdd(&gstat[1], sC[0] + sC[1] + sC[2] + sC[3]);
        __threadfence();
        unsigned t = atomicAdd((unsigned*)(gstat + 2), 1u);
        if (t == (unsigned)(gridDim.x - 1)) {
            float s2 = unsafeAtomicAdd(&gstat[0], 0.f);   // L2 reads
            float c2 = unsafeAtomicAdd(&gstat[1], 0.f);
            out[0] = s2 / fmaxf(c2, 1.f);
        }
    }
}

extern "C" void kernel_launch(void* const* d_in, const int* in_sizes, int n_in,
                              void* d_out, int out_size, void* d_ws, size_t ws_size,
                              hipStream_t stream) {
    const float* F = (const float*)d_in[0];
    const int* labels = (const int*)d_in[1];
    float* out = (float*)d_out;

    char* ws = (char*)d_ws;
    __hip_bfloat16* Fb = (__hip_bfloat16*)ws;                        // 2 MB
    size_t off = (size_t)NROWS * DIM * 2;
    float* x2 = (float*)(ws + off);    off += (size_t)NROWS * 4;     // 32 KB
    float4* corr = (float4*)(ws + off); off += (size_t)NROWS * 16;   // 128 KB
    float2* partial = (float2*)(ws + off);                           // 1 MB
    off += (size_t)JSPLIT * NROWS * 8;
    float* gstat = (float*)(ws + off);                               // 16 B

    prep_kernel<<<NROWS / 4, 256, 0, stream>>>(F, Fb, x2, gstat);
    pairs_kernel<<<dim3(NROWS / 64, JSPLIT), 256, 0, stream>>>(
        Fb, x2, labels, partial, corr);
    finalize_kernel<<<NROWS / 256, 256, 0, stream>>>(partial, corr, gstat, out);
}

// Round 20
// 113.719 us; speedup vs baseline: 1.0414x; 1.0239x over previous
//
#include <hip/hip_runtime.h>
#include <hip/hip_bf16.h>

// TripletLoss N=8192, D=128. Round 21: ledger-decomposed best cell.
// Head/loop decomposition across rounds: {2-barrier, dbuf} x {bucket-read,
// label-scan} -- r8(2bar+bucket)=49.5, r17(dbuf+scan)=55.0, r19(2bar+scan)
// =63.1. Loop delta: dbuf -8us; head delta: bucket -13us. The in-kernel
// label scan (8 serial global-load iters per block) was the hidden cost;
// r10's ledger shows dispatch count doesn't change fixed overhead, so the
// memset+bucket-build comes back for free. This round: r17's pipelined
// small-dbuf loop + r8's bucket-read head (bf16 dots from Fb+x2).
// t-units: Fb,x2 pre-scaled by AK1=sqrt2*log2(e); C-init -(x2i+x2j)/2 =>
// acc = -AK1^2*d2/2; t=sqrt(-acc); exp(-dist)=exp2(-t); dist=t*ln2;
// positives exp(dist-30)=exp2(t+C2).

typedef __bf16 bf16x8 __attribute__((ext_vector_type(8)));
typedef float f32x4 __attribute__((ext_vector_type(4)));

#define NROWS 8192
#define DIM 128
#define JTILE 32
#define LDS_STRIDE 136    // 128+8 bf16 pad: 272B rows (17x16B, odd -> b128 spread)
#define NLABELS 512
#define GCAP 64           // max rows/label (E=16; P(>64) ~ 1e-30)
#define JSPLIT 16
#define JSPAN (NROWS / JSPLIT)   // 512
#define JITERS (JSPAN / JTILE)   // 16
#define MARGIN_F 0.3f
#define AK1F 2.04027892f      // sqrt2 * log2(e)
#define EPS_T 2.08137e-8f     // AK1^2 * 5e-9 (matches reference clip(d2,1e-8))
#define C2F (-43.2808512f)    // -30*log2(e)
#define LN2F 0.69314718f

// ------- kernel 1: scaled bf16 cast + row norms + label buckets + gstat ----
__global__ __launch_bounds__(256) void prep_kernel(const float* __restrict__ F,
                                                   const int* __restrict__ labels,
                                                   __hip_bfloat16* __restrict__ Fb,
                                                   float* __restrict__ x2,
                                                   int* __restrict__ gcnt,
                                                   int* __restrict__ gslot) {
    const int tid = threadIdx.x;
    const int wave = tid >> 6, lane = tid & 63;
    const int row = blockIdx.x * 4 + wave;
    float2 f = ((const float2*)(F + (size_t)row * DIM))[lane];
    f.x *= AK1F; f.y *= AK1F;
    ((__hip_bfloat162*)(Fb + (size_t)row * DIM))[lane] = __float22bfloat162_rn(f);
    float ss = f.x * f.x + f.y * f.y;
#pragma unroll
    for (int m = 32; m > 0; m >>= 1) ss += __shfl_xor(ss, m, 64);
    if (lane == 0) {
        x2[row] = ss;
        const int lab = labels[row];
        int pos = atomicAdd(&gcnt[lab], 1);
        if (pos < GCAP) gslot[lab * GCAP + pos] = row;
    }
}

// ---------------- kernel 2: pipelined GEMM + mining; bucket head on by<4 ---
// 64 i-rows per block, 16 per wave (16x16 MFMA); 32-col j-tiles (2 jt groups).
template<bool DIAG>
__device__ __forceinline__ void tile_body(const __hip_bfloat16* __restrict__ sB,
                                          const float* __restrict__ sX2h,
                                          const bf16x8 (&a)[4],
                                          const float (&x2ih)[4],
                                          float (&nl4)[4], float (&ns4)[4],
                                          int lm, int quad, int ig0, int jbase) {
#pragma unroll
    for (int jt = 0; jt < 2; ++jt) {
        const int jl = jt * 16 + lm;
        const __hip_bfloat16* bp = sB + jl * LDS_STRIDE + quad * 8;
        const float xjh = sX2h[jl];
        f32x4 acc;
#pragma unroll
        for (int r = 0; r < 4; ++r) acc[r] = x2ih[r] + xjh;
#pragma unroll
        for (int kc = 0; kc < 4; ++kc) {
            bf16x8 b = *(const bf16x8*)(bp + kc * 32);
            acc = __builtin_amdgcn_mfma_f32_16x16x32_bf16(a[kc], b, acc, 0, 0, 0);
        }
        const int dj = jbase + jl - ig0;   // self-pair iff dj == r
#pragma unroll
        for (int r = 0; r < 4; ++r) {
            float d2h = fmaxf(-acc[r], EPS_T);          // = AK1^2*d2/2, clipped
            float t = __builtin_amdgcn_sqrtf(d2h);      // dist = t*ln2
            float ne = __builtin_amdgcn_exp2f(-t);      // exp(-dist)
            if (DIAG) ne = (dj == r) ? 0.f : ne;
            nl4[r] += ne;
            ns4[r] = fmaf(ne, t, ns4[r]);
        }
    }
}

__global__ __launch_bounds__(256, 3) void pairs_kernel(
        const __hip_bfloat16* __restrict__ Fb,
        const float* __restrict__ x2,
        const int* __restrict__ gcnt,
        const int* __restrict__ gslot,
        float2* __restrict__ partial,
        float4* __restrict__ corr) {
    __shared__ __hip_bfloat16 sB[2][JTILE * LDS_STRIDE];   // 17.4 KB double buffer
    __shared__ float sX2[2][JTILE];                        // -0.5 * x2j

    const int tid = threadIdx.x;
    const int bx = blockIdx.x, by = blockIdx.y;

    // ---- bucket-read corr head: 512 blocks (by<4), one label each ---------
    if (by < 4) {
        const int L = by * 128 + bx;
        const int cnt = gcnt[L];
        const int gsz = cnt < GCAP ? cnt : GCAP;
        if (gsz > 0) {
            float* sAcc = (float*)sB;          // overlay, pre-staging
            float* plA = sAcc;
            float* psA = sAcc + GCAP;
            float* nlA = sAcc + 2 * GCAP;
            float* nsA = sAcc + 3 * GCAP;
            if (tid < GCAP) { plA[tid] = 0.f; psA[tid] = 0.f; nlA[tid] = 0.f; nsA[tid] = 0.f; }
            __syncthreads();
            const int npair = gsz * gsz;
            for (int p = tid; p < npair; p += 256) {
                const int aI = p / gsz, bI = p - aI * gsz;
                if (aI == bI) continue;
                const int ia = gslot[L * GCAP + aI];
                const int ib = gslot[L * GCAP + bI];
                const bf16x8* pa = (const bf16x8*)(Fb + (size_t)ia * DIM);
                const bf16x8* pb = (const bf16x8*)(Fb + (size_t)ib * DIM);
                float dot = 0.f;
#pragma unroll 4
                for (int u = 0; u < 16; ++u) {
                    bf16x8 va = pa[u], vb = pb[u];
#pragma unroll
                    for (int e = 0; e < 8; ++e)
                        dot = fmaf((float)va[e], (float)vb[e], dot);
                }
                float d2h = fmaxf(0.5f * (x2[ia] + x2[ib]) - dot, EPS_T);  // t-units
                float t = __builtin_amdgcn_sqrtf(d2h);
                float ne = __builtin_amdgcn_exp2f(-t);
                float pe = __builtin_amdgcn_exp2f(t + C2F);
                unsafeAtomicAdd(&nlA[aI], ne);
                unsafeAtomicAdd(&nsA[aI], ne * t);
                unsafeAtomicAdd(&plA[aI], pe);
                unsafeAtomicAdd(&psA[aI], pe * t);
            }
            __syncthreads();
            if (tid < gsz)
                corr[gslot[L * GCAP + tid]] =
                    make_float4(plA[tid], psA[tid], -nlA[tid], -nsA[tid]);
        }
        __syncthreads();   // head's LDS use done before staging overwrites
    }

    // ---- A-fragments + x2i (r8 mapping) ----
    const int wave = tid >> 6;
    const int lane = tid & 63;
    const int quad = lane >> 4;
    const int lm = lane & 15;
    const int rbase = bx * 64 + wave * 16;

    bf16x8 a[4];
#pragma unroll
    for (int kc = 0; kc < 4; ++kc)
        a[kc] = *(const bf16x8*)(Fb + (size_t)(rbase + lm) * DIM + kc * 32 + quad * 8);

    const int ig0 = rbase + quad * 4;
    float x2ih[4];
#pragma unroll
    for (int r = 0; r < 4; ++r) x2ih[r] = -0.5f * x2[ig0 + r];

    float nl4[4] = {0,0,0,0}, ns4[4] = {0,0,0,0};

    const int j0 = by * JSPAN;
    // block's 64 i-rows span two 32-col j-tiles: jb = 2*bx - 16*by and +1
    const int djb0 = 2 * bx - by * JITERS;

    // ---- pipelined j-loop: issue-early / write-late, 1 barrier per tile ---
    const int c0 = tid, c1 = tid + 256;      // 512 chunks = 32 rows x 16
    uint4 st0, st1;
    float xv;
#define LOADTILE(JB) do {                                                      \
        const size_t jo = (size_t)(JB);                                        \
        st0 = *(const uint4*)(Fb + (jo + (c0 >> 4)) * DIM + (c0 & 15) * 8);    \
        st1 = *(const uint4*)(Fb + (jo + (c1 >> 4)) * DIM + (c1 & 15) * 8);    \
        if (tid < JTILE) xv = x2[jo + tid];                                    \
    } while (0)
#define WRITETILE(B) do {                                                      \
        __hip_bfloat16* sb = sB[B];                                            \
        *(uint4*)(sb + (c0 >> 4) * LDS_STRIDE + (c0 & 15) * 8) = st0;          \
        *(uint4*)(sb + (c1 >> 4) * LDS_STRIDE + (c1 & 15) * 8) = st1;          \
        if (tid < JTILE) sX2[B][tid] = -0.5f * xv;                             \
    } while (0)

    LOADTILE(j0);          // prologue: tile 0
    WRITETILE(0);
    __syncthreads();
    int cur = 0;
    for (int jb = 0; jb < JITERS; ++jb) {
        if (jb + 1 < JITERS) LOADTILE(j0 + (jb + 1) * JTILE);  // in flight
        const int jbase = j0 + jb * JTILE;                     // during compute
        if ((unsigned)(jb - djb0) <= 1u)
            tile_body<true >(sB[cur], sX2[cur], a, x2ih, nl4, ns4, lm, quad, ig0, jbase);
        else
            tile_body<false>(sB[cur], sX2[cur], a, x2ih, nl4, ns4, lm, quad, ig0, jbase);
        if (jb + 1 < JITERS) WRITETILE(cur ^ 1);   // other buffer: no race
        __syncthreads();   // writes visible; all waves done reading buf[cur]
        cur ^= 1;
    }
#undef LOADTILE
#undef WRITETILE

    // reduce over the 16 lanes (lm) sharing each i-row
#pragma unroll
    for (int m = 1; m < 16; m <<= 1) {
#pragma unroll
        for (int r = 0; r < 4; ++r) {
            nl4[r] += __shfl_xor(nl4[r], m, 64);
            ns4[r] += __shfl_xor(ns4[r], m, 64);
        }
    }
    if (lm == 0) {
#pragma unroll
        for (int r = 0; r < 4; ++r)
            partial[(size_t)by * NROWS + ig0 + r] = make_float2(nl4[r], ns4[r]);
    }
}

// ---------------- kernel 3: per-row loss, reduce, final divide -------------
__global__ __launch_bounds__(256) void finalize_kernel(const float2* __restrict__ partial,
                                                       const float4* __restrict__ corr,
                                                       float* __restrict__ gstat,
                                                       float* __restrict__ out) {
    const int row = blockIdx.x * 256 + threadIdx.x;
    float4 c = corr[row];
    float nl = c.z, ns = c.w;    // negative corrections (subtract same-label mass)
#pragma unroll
    for (int s = 0; s < JSPLIT; ++s) {
        float2 p = partial[(size_t)s * NROWS + row];
        nl += p.x; ns += p.y;
    }
    float sum = 0.f, cnt = 0.f;
    if (c.x > 0.f && nl > 0.f) {
        float x = fmaf(LN2F, c.y / c.x - ns / nl, MARGIN_F);   // wp - wn + margin
        sum = fmaxf(x, 0.f) + log1pf(__expf(-fabsf(x)));       // stable softplus
        cnt = 1.f;
    }
#pragma unroll
    for (int m = 32; m > 0; m >>= 1) {
        sum += __shfl_xor(sum, m, 64);
        cnt += __shfl_xor(cnt, m, 64);
    }
    __shared__ float sS[4], sC[4];
    const int wave = threadIdx.x >> 6, lane = threadIdx.x & 63;
    if (lane == 0) { sS[wave] = sum; sC[wave] = cnt; }
    __syncthreads();
    if (threadIdx.x == 0) {
        unsafeAtomicAdd(&gstat[0], sS[0] + sS[1] + sS[2] + sS[3]);
        unsafeAtomicAdd(&gstat[1], sC[0] + sC[1] + sC[2] + sC[3]);
        __threadfence();
        unsigned t = atomicAdd((unsigned*)(gstat + 2), 1u);
        if (t == (unsigned)(gridDim.x - 1)) {
            float s2 = unsafeAtomicAdd(&gstat[0], 0.f);   // L2 reads
            float c2 = unsafeAtomicAdd(&gstat[1], 0.f);
            out[0] = s2 / fmaxf(c2, 1.f);
        }
    }
}

extern "C" void kernel_launch(void* const* d_in, const int* in_sizes, int n_in,
                              void* d_out, int out_size, void* d_ws, size_t ws_size,
                              hipStream_t stream) {
    const float* F = (const float*)d_in[0];
    const int* labels = (const int*)d_in[1];
    float* out = (float*)d_out;

    char* ws = (char*)d_ws;
    __hip_bfloat16* Fb = (__hip_bfloat16*)ws;                        // 2 MB
    size_t off = (size_t)NROWS * DIM * 2;
    float* x2 = (float*)(ws + off);    off += (size_t)NROWS * 4;     // 32 KB
    float4* corr = (float4*)(ws + off); off += (size_t)NROWS * 16;   // 128 KB
    int* gcnt = (int*)(ws + off);      off += (size_t)NLABELS * 4;   // 2 KB
    float* gstat = (float*)(ws + off); off += 16;                    // 16 B
    int* gslot = (int*)(ws + off);     off += (size_t)NLABELS * GCAP * 4; // 128 KB
    float2* partial = (float2*)(ws + off);                           // 1 MB

    // zero gcnt (512 ints) + gstat (4 floats) — contiguous region
    hipMemsetAsync(gcnt, 0, (size_t)NLABELS * 4 + 16, stream);
    prep_kernel<<<NROWS / 4, 256, 0, stream>>>(F, labels, Fb, x2, gcnt, gslot);
    pairs_kernel<<<dim3(NROWS / 64, JSPLIT), 256, 0, stream>>>(
        Fb, x2, gcnt, gslot, partial, corr);
    finalize_kernel<<<NROWS / 256, 256, 0, stream>>>(partial, corr, gstat, out);
}